// Round 3
// baseline (420.001 us; speedup 1.0000x reference)
//
#include <hip/hip_runtime.h>
#include <math.h>

#define B 64
#define DIM 10
#define V_CH 5
#define P 50176
#define C 4

#define XCH 7                   // chunks per output row
#define CHUNK (P / XCH)         // 7168 = 28*256 floats
#define NWSUM (B * V_CH * XCH)  // 2240 blocks
#define NMAP  (B * C * XCH)     // 1792 blocks  -> 4032 total

typedef float f32x4 __attribute__((ext_vector_type(4)));

// ---------------------------------------------------------------------------
// Single fused kernel. Every block:
//   1. (wsum blocks) prefetch first v tile — covers the MLP bubble
//   2. redundantly computes attn[b][0..3] for its own batch b in LDS
//      (MLP is ~2-3k cycles; 4032 blocks => ~5 us machine-wide, overlapped)
//   3. streams its chunk: weighted sum (y<320 rows) or attn_map broadcast
// No workspace, no second dispatch, no inter-kernel serialization.
// ---------------------------------------------------------------------------
__global__ __launch_bounds__(256) void fused_kernel(
    const float* __restrict__ q,    // (B,10,1)
    const float* __restrict__ k,    // (B,10,1,C)
    const f32x4* __restrict__ v4,   // (B,V_CH,P) float4s (c innermost)
    const float* __restrict__ md,   // (B,C)
    const float* __restrict__ qw1, const float* __restrict__ qb1,
    const float* __restrict__ qw2, const float* __restrict__ qb2,
    const float* __restrict__ qg,  const float* __restrict__ qbeta,
    const float* __restrict__ kw1, const float* __restrict__ kb1,
    const float* __restrict__ kw2, const float* __restrict__ kb2,
    const float* __restrict__ kg,  const float* __restrict__ kbeta,
    float* __restrict__ out)        // out (B*V_CH*P) then attn_map (B*C*P)
{
    const int blk = blockIdx.x;
    const int t   = threadIdx.x;

    const bool is_map = (blk >= NWSUM);
    int idx, ch, b;
    if (!is_map) {                       // idx = b*V_CH + vc
        idx = blk / XCH; ch = blk % XCH; b = idx / V_CH;
    } else {                             // idx = b*C + c
        const int m = blk - NWSUM;
        idx = m / XCH; ch = m % XCH; b = idx / C;
    }

    // element-index base within a P-row (valid for both v4 and out scales)
    const size_t wbase = (size_t)idx * P + (size_t)ch * CHUNK;

    // ---- prefetch iteration 0 (wsum only) before the MLP ----
    f32x4 pre = {0.f, 0.f, 0.f, 0.f};
    if (!is_map) pre = __builtin_nontemporal_load(v4 + wbase + t);

    __shared__ float xs[DIM];
    __shared__ float h1s[128];
    __shared__ float h2s[16];
    __shared__ float e[5][16];   // e[0]=qe, e[1..4]=ke[c]
    __shared__ float lg[4];
    __shared__ float as[4];

    for (int h = 0; h < 5; ++h) {
        const float *w1, *b1, *w2, *b2, *g, *beta;
        if (h == 0) { w1 = qw1; b1 = qb1; w2 = qw2; b2 = qb2; g = qg; beta = qbeta; }
        else        { w1 = kw1; b1 = kb1; w2 = kw2; b2 = kb2; g = kg; beta = kbeta; }

        if (t < DIM) {
            xs[t] = (h == 0) ? q[b * DIM + t]
                             : k[(b * DIM + t) * C + (h - 1)];
        }
        __syncthreads();

        // 10 -> 128 + LeakyReLU(0.1); one hidden unit per thread (t<128 only!)
        if (t < 128) {
            float acc = b1[t];
            #pragma unroll
            for (int d = 0; d < DIM; ++d) acc += w1[t * DIM + d] * xs[d];
            h1s[t] = (acc >= 0.f) ? acc : 0.1f * acc;
        }
        __syncthreads();

        // 128 -> 16
        if (t < 16) {
            float acc = b2[t];
            #pragma unroll
            for (int i = 0; i < 128; ++i) acc += w2[t * 128 + i] * h1s[i];
            h2s[t] = acc;
        }
        __syncthreads();

        // LayerNorm(16)
        if (t < 16) {
            float mu = 0.f;
            #pragma unroll
            for (int j = 0; j < 16; ++j) mu += h2s[j];
            mu *= (1.f / 16.f);
            float var = 0.f;
            #pragma unroll
            for (int j = 0; j < 16; ++j) { float d = h2s[j] - mu; var += d * d; }
            var *= (1.f / 16.f);
            e[h][t] = (h2s[t] - mu) / sqrtf(var + 1e-5f) * g[t] + beta[t];
        }
        __syncthreads();
    }

    // logits (scale = 10^-0.5) + dropout mask
    if (t < C) {
        float d = 0.f;
        #pragma unroll
        for (int j = 0; j < 16; ++j) d += e[0][j] * e[1 + t][j];
        lg[t] = d * 0.31622776601683794f - md[b * C + t] * 1e5f;
    }
    __syncthreads();

    // softmax(logits / 10) over C=4
    if (t < C) {
        float m = fmaxf(fmaxf(lg[0], lg[1]), fmaxf(lg[2], lg[3])) * 0.1f;
        float s = 0.f;
        #pragma unroll
        for (int c = 0; c < C; ++c) s += expf(lg[c] * 0.1f - m);
        as[t] = expf(lg[t] * 0.1f - m) / s;
    }
    __syncthreads();

    if (!is_map) {
        const f32x4 a = { as[0], as[1], as[2], as[3] };
        // consume prefetched iteration 0
        {
            const float r = pre.x * a.x + pre.y * a.y + pre.z * a.z + pre.w * a.w;
            __builtin_nontemporal_store(r, out + wbase + t);
        }
        for (int i = 1; i < CHUNK / 256; ++i) {   // 27 more iterations
            const int p = i * 256 + t;
            const f32x4 vv = __builtin_nontemporal_load(v4 + wbase + p);
            const float r = vv.x * a.x + vv.y * a.y + vv.z * a.z + vv.w * a.w;
            __builtin_nontemporal_store(r, out + wbase + p);
        }
    } else {
        const float val = as[idx & 3];            // c = idx % C
        float* mp = out + (size_t)(B * V_CH) * P + wbase;
        const f32x4 r = { val, val, val, val };
        #pragma unroll
        for (int i = 0; i < CHUNK / 1024; ++i)    // 7 f32x4 stores, no tail
            __builtin_nontemporal_store(r, (f32x4*)mp + i * 256 + t);
    }
}

extern "C" void kernel_launch(void* const* d_in, const int* in_sizes, int n_in,
                              void* d_out, int out_size, void* d_ws, size_t ws_size,
                              hipStream_t stream) {
    const float* q     = (const float*)d_in[0];
    const float* k     = (const float*)d_in[1];
    const float* v     = (const float*)d_in[2];
    const float* md    = (const float*)d_in[3];
    const float* qw1   = (const float*)d_in[4];
    const float* qb1   = (const float*)d_in[5];
    const float* qw2   = (const float*)d_in[6];
    const float* qb2   = (const float*)d_in[7];
    const float* qg    = (const float*)d_in[8];
    const float* qbeta = (const float*)d_in[9];
    const float* kw1   = (const float*)d_in[10];
    const float* kb1   = (const float*)d_in[11];
    const float* kw2   = (const float*)d_in[12];
    const float* kb2   = (const float*)d_in[13];
    const float* kg    = (const float*)d_in[14];
    const float* kbeta = (const float*)d_in[15];

    fused_kernel<<<NWSUM + NMAP, 256, 0, stream>>>(
        q, k, (const f32x4*)v, md,
        qw1, qb1, qw2, qb2, qg, qbeta,
        kw1, kb1, kw2, kb2, kg, kbeta,
        (float*)d_out);
}